// Round 5
// baseline (141.198 us; speedup 1.0000x reference)
//
#include <hip/hip_runtime.h>
#include <hip/hip_cooperative_groups.h>
#include <stdint.h>

namespace cg = cooperative_groups;

#define NUM_CLASSES 80
#define TOPK 1000
#define NBINS 4096          // top 12 bits of flipped float key
#define CAP 4096            // candidate capacity
#define MAXPC 128           // max boxes per class in NMS lists
#define CONF_THRESH 0.05f
#define NMS_THRESH 0.6f
#define CTR_CLAMP 32.0f
#define SCALE_CLAMP 4.135166556742356f  // log(1000/16)
#define ANCH_STRIDE 32.0f
#define GRID_BLOCKS 64

__device__ __forceinline__ unsigned int flip_key(unsigned int u) {
    return (u & 0x80000000u) ? ~u : (u | 0x80000000u);
}
__device__ __forceinline__ float unflip_key(unsigned int k) {
    unsigned int u = (k & 0x80000000u) ? (k ^ 0x80000000u) : ~k;
    return __uint_as_float(u);
}

struct SharedPool {
    union {
        struct { unsigned int h[NBINS]; unsigned int suf[1024]; } hist;   // 20480 B
        uint64_t sk[CAP];                                                  // 32768 B
        struct {
            float bx1[TOPK], by1[TOPK], bx2[TOPK], by2[TOPK], bar[TOPK];  // 20000
            int skeep[TOPK];                                               // 4000
            unsigned short clist[NUM_CLASSES * MAXPC];                     // 20480
            int scount[NUM_CLASSES];                                       // 320
            unsigned int chunkCnt[16][NUM_CLASSES];                        // 5120
            unsigned int chunkBase[16][NUM_CLASSES];                       // 5120
        } fin;                                                             // 55040 B
    };
};

__global__ __launch_bounds__(1024) void fused_k(
    const float* __restrict__ cls, const float* __restrict__ regp,
    const float* __restrict__ anchor_size,
    const int* __restrict__ fmp_w_p, const int* __restrict__ img_h_p,
    const int* __restrict__ img_w_p, int ka, int M,
    unsigned int* __restrict__ hist, unsigned int* __restrict__ counter,
    unsigned int* __restrict__ binB,
    uint64_t* __restrict__ cand, uint64_t* __restrict__ sorted,
    float* __restrict__ out)
{
    cg::grid_group grid = cg::this_grid();
    __shared__ SharedPool sp;

    int tid = threadIdx.x;
    int blk = blockIdx.x;
    int gid = blk * 1024 + tid;
    int nthr = GRID_BLOCKS * 1024;

    // ---- P0: zero global accumulators (atomics -> coherence point); local LDS hist ----
    if (gid < NBINS) atomicExch(&hist[gid], 0u);
    if (gid == NBINS) atomicExch(counter, 0u);
    for (int i = tid; i < NBINS; i += 1024) sp.hist.h[i] = 0u;
    __syncthreads();

    const float4* cls4 = (const float4*)cls;
    int M4 = M >> 2;
    for (int i = gid; i < M4; i += nthr) {
        float4 v = cls4[i];
        atomicAdd(&sp.hist.h[flip_key(__float_as_uint(v.x)) >> 20], 1u);
        atomicAdd(&sp.hist.h[flip_key(__float_as_uint(v.y)) >> 20], 1u);
        atomicAdd(&sp.hist.h[flip_key(__float_as_uint(v.z)) >> 20], 1u);
        atomicAdd(&sp.hist.h[flip_key(__float_as_uint(v.w)) >> 20], 1u);
    }
    for (int i = (M4 << 2) + gid; i < M; i += nthr)
        atomicAdd(&sp.hist.h[flip_key(__float_as_uint(cls[i])) >> 20], 1u);
    __syncthreads();
    grid.sync();   // zeros visible everywhere; local hists complete

    // ---- P1: merge local hists into global (device-scope atomics) ----
    for (int i = tid; i < NBINS; i += 1024) {
        unsigned int v = sp.hist.h[i];
        if (v) atomicAdd(&hist[i], v);
    }
    grid.sync();   // merged hist complete

    // ---- P2: block 0 suffix-scans hist, finds boundary bin ----
    if (blk == 0) {
        unsigned int hv[4];
        int base = tid * 4;
        unsigned int s = 0;
        #pragma unroll
        for (int b = 0; b < 4; ++b) { hv[b] = atomicAdd(&hist[base + b], 0u); s += hv[b]; }
        sp.hist.suf[tid] = s;
        __syncthreads();
        for (int off = 1; off < 1024; off <<= 1) {
            unsigned int v = (tid + off < 1024) ? sp.hist.suf[tid + off] : 0u;
            __syncthreads();
            sp.hist.suf[tid] += v;
            __syncthreads();
        }
        unsigned int mine = sp.hist.suf[tid];
        unsigned int nxt = (tid < 1023) ? sp.hist.suf[tid + 1] : 0u;
        if (mine >= (unsigned)TOPK && nxt < (unsigned)TOPK) {
            unsigned int c = nxt;
            for (int b = base + 3; b >= base; --b) {
                c += hv[b];
                if (c >= (unsigned)TOPK) { atomicExch(binB, (unsigned int)b); break; }
            }
        }
    }
    grid.sync();   // binB ready

    // ---- P3: grid-wide compact of candidates >= boundary bin ----
    {
        unsigned int b = *binB;   // plain load after grid.sync acquire; written via atomic
        int lane = tid & 63;
        for (int i = gid; i < M4; i += nthr) {
            float4 v = cls4[i];
            unsigned int k[4];
            k[0] = flip_key(__float_as_uint(v.x));
            k[1] = flip_key(__float_as_uint(v.y));
            k[2] = flip_key(__float_as_uint(v.z));
            k[3] = flip_key(__float_as_uint(v.w));
            #pragma unroll
            for (int j = 0; j < 4; ++j) {
                bool pred = ((k[j] >> 20) >= b);
                unsigned long long m = __ballot(pred);
                if (m) {
                    int leader = __ffsll((long long)m) - 1;
                    unsigned int base2 = 0;
                    if (lane == leader) base2 = atomicAdd(counter, (unsigned int)__popcll(m));
                    base2 = (unsigned int)__shfl((int)base2, leader);
                    if (pred) {
                        unsigned int p = base2 + (unsigned int)__popcll(m & ((1ull << lane) - 1ull));
                        unsigned int gi = (unsigned int)(i * 4 + j);
                        if (p < (unsigned)CAP)
                            cand[p] = ((uint64_t)k[j] << 32) | (uint64_t)(0xFFFFFFFFu - gi);
                    }
                }
            }
        }
        for (int i = (M4 << 2) + gid; i < M; i += nthr) {
            unsigned int key = flip_key(__float_as_uint(cls[i]));
            if ((key >> 20) >= b) {
                unsigned int p = atomicAdd(counter, 1u);
                if (p < (unsigned)CAP)
                    cand[p] = ((uint64_t)key << 32) | (uint64_t)(0xFFFFFFFFu - (unsigned int)i);
            }
        }
        __threadfence();   // release cand stores
    }
    grid.sync();   // cand + counter ready

    // ---- P4: rank selection: sorted[rank] = key (exact stable top-k) ----
    {
        unsigned int cnt0 = *counter;
        int N = (cnt0 < (unsigned)CAP) ? (int)cnt0 : CAP;
        for (int i = tid; i < N; i += 1024) sp.sk[i] = cand[i];
        __syncthreads();
        int c = blk * 64 + (tid >> 4);   // 16 threads per candidate
        int s = tid & 15;
        if (c < N) {
            uint64_t my = sp.sk[c];
            unsigned int cnt = 0;
            for (int j = s; j < N; j += 16) cnt += (sp.sk[j] > my) ? 1u : 0u;
            cnt += (unsigned int)__shfl_xor((int)cnt, 1);
            cnt += (unsigned int)__shfl_xor((int)cnt, 2);
            cnt += (unsigned int)__shfl_xor((int)cnt, 4);
            cnt += (unsigned int)__shfl_xor((int)cnt, 8);
            if (s == 0 && cnt < (unsigned)TOPK) sorted[cnt] = my;
        }
        __threadfence();   // release sorted stores
    }
    grid.sync();   // sorted[0..999] ready

    // ---- P5: block 0: decode + ballot class lists + per-class wave NMS + output ----
    if (blk != 0) return;
    {
        int fmp_w = *fmp_w_p;
        float prob = 0.0f, lblf = 0.0f;
        float b0 = 0.f, b1 = 0.f, b2 = 0.f, b3 = 0.f;
        int lab = 255;
        if (tid < TOPK) {
            uint64_t k = sorted[tid];
            unsigned int idx = 0xFFFFFFFFu - (unsigned int)(k & 0xFFFFFFFFull);
            float logit = unflip_key((unsigned int)(k >> 32));
            prob = 1.0f / (1.0f + expf(-logit));
            lab = (int)(idx % NUM_CLASSES);
            int aidx = (int)(idx / NUM_CLASSES);
            int g = aidx / ka, kk = aidx % ka;
            int xg = g % fmp_w, yg = g / fmp_w;
            float ax = (xg + 0.5f) * ANCH_STRIDE, ay = (yg + 0.5f) * ANCH_STRIDE;
            float aw = anchor_size[kk * 2 + 0], ah = anchor_size[kk * 2 + 1];
            float r0 = regp[aidx * 4 + 0], r1 = regp[aidx * 4 + 1];
            float r2 = regp[aidx * 4 + 2], r3 = regp[aidx * 4 + 3];
            float ox = fminf(fmaxf(r0 * aw, -CTR_CLAMP), CTR_CLAMP);
            float oy = fminf(fmaxf(r1 * ah, -CTR_CLAMP), CTR_CLAMP);
            float cx = ax + ox, cy = ay + oy;
            float w = aw * expf(fminf(r2, SCALE_CLAMP));
            float h = ah * expf(fminf(r3, SCALE_CLAMP));
            b0 = cx - 0.5f * w; b1 = cy - 0.5f * h;
            b2 = cx + 0.5f * w; b3 = cy + 0.5f * h;
            lblf = (float)lab;
            sp.fin.bx1[tid] = b0; sp.fin.by1[tid] = b1;
            sp.fin.bx2[tid] = b2; sp.fin.by2[tid] = b3;
            sp.fin.bar[tid] = (b2 - b0) * (b3 - b1);   // class offset cancels within-class
            sp.fin.skeep[tid] = (prob > CONF_THRESH) ? 1 : 0;
        }

        // ballot-based stable per-class lists
        int wv = tid >> 6, lane = tid & 63;
        unsigned long long ltmask = (lane == 0) ? 0ull : ((~0ull) >> (64 - lane));
        unsigned int mypos = 0;
        for (int c = 0; c < NUM_CLASSES; ++c) {
            unsigned long long m = __ballot(lab == c);
            if (lab == c) mypos = (unsigned int)__popcll(m & ltmask);
            if (lane == 0) sp.fin.chunkCnt[wv][c] = (unsigned int)__popcll(m);
        }
        __syncthreads();
        if (tid < NUM_CLASSES) {
            unsigned int run = 0;
            for (int w = 0; w < 16; ++w) { sp.fin.chunkBase[w][tid] = run; run += sp.fin.chunkCnt[w][tid]; }
            sp.fin.scount[tid] = (run < (unsigned)MAXPC) ? (int)run : MAXPC;
        }
        __syncthreads();
        if (tid < TOPK) {
            unsigned int p = sp.fin.chunkBase[wv][lab] + mypos;
            if (p < (unsigned)MAXPC) sp.fin.clist[lab * MAXPC + p] = (unsigned short)tid;
        }
        __syncthreads();

        // per-class greedy NMS: one wave per class, shuffle broadcast, no barriers.
        // Cross-class IoU under CLASS_OFFSET=1e5 is ~1e-56 (never > 0.6); offset
        // cancels within-class, so per-class greedy on raw coords is exact.
        for (int c = wv; c < NUM_CLASSES; c += 16) {
            int n = sp.fin.scount[c];
            if (n <= 0) continue;
            int k0 = lane, k1 = lane + 64;
            int rk0 = -1, rk1 = -1, kp0 = 0, kp1 = 0;
            float x10=0,y10=0,x20=0,y20=0,a0=0, x11=0,y11=0,x21=0,y21=0,a1=0;
            if (k0 < n) {
                rk0 = sp.fin.clist[c * MAXPC + k0];
                x10 = sp.fin.bx1[rk0]; y10 = sp.fin.by1[rk0];
                x20 = sp.fin.bx2[rk0]; y20 = sp.fin.by2[rk0];
                a0 = sp.fin.bar[rk0]; kp0 = sp.fin.skeep[rk0];
            }
            if (k1 < n) {
                rk1 = sp.fin.clist[c * MAXPC + k1];
                x11 = sp.fin.bx1[rk1]; y11 = sp.fin.by1[rk1];
                x21 = sp.fin.bx2[rk1]; y21 = sp.fin.by2[rk1];
                a1 = sp.fin.bar[rk1]; kp1 = sp.fin.skeep[rk1];
            }
            for (int i = 0; i < n; ++i) {
                int src = i & 63;
                int ki; float xi1, yi1, xi2, yi2, ai;
                if (i < 64) {
                    ki = __shfl(kp0, src);
                    xi1 = __shfl(x10, src); yi1 = __shfl(y10, src);
                    xi2 = __shfl(x20, src); yi2 = __shfl(y20, src);
                    ai  = __shfl(a0, src);
                } else {
                    ki = __shfl(kp1, src);
                    xi1 = __shfl(x11, src); yi1 = __shfl(y11, src);
                    xi2 = __shfl(x21, src); yi2 = __shfl(y21, src);
                    ai  = __shfl(a1, src);
                }
                if (ki) {
                    if (k0 > i && kp0) {
                        float xx1 = fmaxf(xi1, x10), yy1 = fmaxf(yi1, y10);
                        float xx2 = fminf(xi2, x20), yy2 = fminf(yi2, y20);
                        float w = fmaxf(1e-28f, xx2 - xx1), h = fmaxf(1e-28f, yy2 - yy1);
                        float inter = w * h;
                        if (inter / (ai + a0 - inter + 1e-14f) > NMS_THRESH) kp0 = 0;
                    }
                    if (k1 > i && kp1) {
                        float xx1 = fmaxf(xi1, x11), yy1 = fmaxf(yi1, y11);
                        float xx2 = fminf(xi2, x21), yy2 = fminf(yi2, y21);
                        float w = fmaxf(1e-28f, xx2 - xx1), h = fmaxf(1e-28f, yy2 - yy1);
                        float inter = w * h;
                        if (inter / (ai + a1 - inter + 1e-14f) > NMS_THRESH) kp1 = 0;
                    }
                }
            }
            if (k0 < n) sp.fin.skeep[rk0] = kp0;
            if (k1 < n) sp.fin.skeep[rk1] = kp1;
        }
        __syncthreads();

        if (tid < TOPK) {
            float keepf = (float)sp.fin.skeep[tid];
            float img_w = (float)(*img_w_p), img_h = (float)(*img_h_p);
            float v0 = fminf(fmaxf(b0 / img_w, 0.0f), 1.0f);
            float v1 = fminf(fmaxf(b1 / img_h, 0.0f), 1.0f);
            float v2 = fminf(fmaxf(b2 / img_w, 0.0f), 1.0f);
            float v3 = fminf(fmaxf(b3 / img_h, 0.0f), 1.0f);
            out[tid * 4 + 0] = v0 * keepf;
            out[tid * 4 + 1] = v1 * keepf;
            out[tid * 4 + 2] = v2 * keepf;
            out[tid * 4 + 3] = v3 * keepf;
            out[4 * TOPK + tid] = prob * keepf;
            out[5 * TOPK + tid] = lblf;
            out[6 * TOPK + tid] = keepf;
        }
    }
}

extern "C" void kernel_launch(void* const* d_in, const int* in_sizes, int n_in,
                              void* d_out, int out_size, void* d_ws, size_t ws_size,
                              hipStream_t stream) {
    const float* cls = (const float*)d_in[0];
    const float* regp = (const float*)d_in[1];
    const float* anchor_size = (const float*)d_in[2];
    const int* fmp_w = (const int*)d_in[4];
    const int* img_h = (const int*)d_in[5];
    const int* img_w = (const int*)d_in[6];
    int M = in_sizes[0];          // m * NUM_CLASSES
    int ka = in_sizes[2] / 2;

    uint8_t* ws = (uint8_t*)d_ws;
    unsigned int* hist = (unsigned int*)ws;                 // [4096]  @0
    unsigned int* counter = (unsigned int*)(ws + 16384);    // @16384
    unsigned int* binB = (unsigned int*)(ws + 16388);       // @16388
    uint64_t* cand = (uint64_t*)(ws + 16400);               // [CAP]   @16400
    uint64_t* sorted = (uint64_t*)(ws + 16400 + CAP * 8);   // [1024]
    float* outp = (float*)d_out;

    void* args[] = { (void*)&cls, (void*)&regp, (void*)&anchor_size,
                     (void*)&fmp_w, (void*)&img_h, (void*)&img_w,
                     (void*)&ka, (void*)&M,
                     (void*)&hist, (void*)&counter, (void*)&binB,
                     (void*)&cand, (void*)&sorted, (void*)&outp };
    hipLaunchCooperativeKernel((void*)fused_k, dim3(GRID_BLOCKS), dim3(1024),
                               args, 0, stream);
}